// Round 7
// baseline (103.180 us; speedup 1.0000x reference)
//
#include <hip/hip_runtime.h>
#include <hip/hip_cooperative_groups.h>

namespace cg = cooperative_groups;

// Problem constants (fixed by setup_inputs)
#define BB 16
#define SS 1024
#define NW 8
#define QB 64
#define NH 4
#define NM 55            // moments (j,i), j+i <= 9
#define NJOB (NH * NM)   // 220

// ws: partial moments only: [BB][16][NJOB] floats = 225 KB
__global__ __launch_bounds__(1024)
void mhaq_fused(const float* __restrict__ x, const int* __restrict__ mask,
                const float* __restrict__ theta, const float* __restrict__ wout,
                float* __restrict__ ws, float* __restrict__ out)
{
    __shared__ float P[NH][QB][4];   // per (head, local row): u, v, mf, 0 (mask info)
    __shared__ float Qf[QB][NW];     // unmasked q features for this chunk
    __shared__ float W[64];          // w_out
    __shared__ float Traw[NH][NM];
    __shared__ float Ts[NH][9][12], Ta[NH][9][12], Tb[NH][9][12];
    __shared__ float O[QB][NW];

    const int tid = threadIdx.x;
    const int b   = blockIdx.x >> 4;
    const int qc  = blockIdx.x & 15;

    // ---------- phase 1a: features for this chunk's 64 rows ----------
    // g_i = cos(x_i + th_i); h0 = g1..g7, hw = g0..gw
    if (tid < QB) {
        const int row = qc * QB + tid;
        const float* xr = x + ((size_t)b * SS + row) * NW;
        const float4 r0 = *reinterpret_cast<const float4*>(xr);
        const float4 r1 = *reinterpret_cast<const float4*>(xr + 4);
        float g[NW];
        g[0] = __cosf(r0.x + theta[0]); g[1] = __cosf(r0.y + theta[1]);
        g[2] = __cosf(r0.z + theta[2]); g[3] = __cosf(r0.w + theta[3]);
        g[4] = __cosf(r1.x + theta[4]); g[5] = __cosf(r1.y + theta[5]);
        g[6] = __cosf(r1.z + theta[6]); g[7] = __cosf(r1.w + theta[7]);
        float h[NW];
        h[1] = g[0] * g[1]; h[2] = h[1] * g[2]; h[3] = h[2] * g[3];
        h[4] = h[3] * g[4]; h[5] = h[4] * g[5]; h[6] = h[5] * g[6];
        h[7] = h[6] * g[7];
        h[0] = (g[1] * g[2]) * (g[3] * g[4]) * ((g[5] * g[6]) * g[7]);
        const float mf = (mask[b * SS + row] != 0) ? 1.0f : 0.0f;
#pragma unroll
        for (int w = 0; w < NW; ++w) Qf[tid][w] = h[w];   // unmasked (q side)
#pragma unroll
        for (int hd = 0; hd < NH; ++hd) {
            P[hd][tid][0] = h[2 * hd];
            P[hd][tid][1] = h[2 * hd + 1];
            P[hd][tid][2] = mf;
            P[hd][tid][3] = 0.0f;
        }
    }
    if (tid < 64) W[tid] = wout[tid];
    __syncthreads();

    // ---------- phase 1b: partial moments over this chunk's 64 keys ----------
    {
        const int jm = tid >> 2;
        const int kc = tid & 3;
        float acc = 0.0f;
        if (jm < NJOB) {
            const int hh = jm / NM;
            int mm = jm % NM, s = 0;
            while (mm > s) { mm -= s + 1; ++s; }   // triangle decode
            const int j = mm, i = s - mm;          // j+i = s <= 9
            const bool j1 = j & 1, j2 = j & 2, j4 = j & 4, j8 = j & 8;
            const bool i1 = i & 1, i2 = i & 2, i4 = i & 4, i8 = i & 8;
#pragma unroll
            for (int it = 0; it < 16; ++it) {
                const int k = kc * 16 + it;
                const float4 uvm = *reinterpret_cast<const float4*>(&P[hh][k][0]);
                const float u = uvm.x, v = uvm.y, mf = uvm.z;
                const float u2 = u * u, u4 = u2 * u2, u8 = u4 * u4;
                const float v2 = v * v, v4 = v2 * v2, v8 = v4 * v4;
                float pu = (j1 ? u : 1.0f) * (j2 ? u2 : 1.0f);
                pu *= (j4 ? u4 : 1.0f); pu *= (j8 ? u8 : 1.0f);
                float pv = (i1 ? v : 1.0f) * (i2 ? v2 : 1.0f);
                pv *= (i4 ? v4 : 1.0f); pv *= (i8 ? v8 : 1.0f);
                acc = __builtin_fmaf(mf * pu, pv, acc);
            }
        }
        acc += __shfl_xor(acc, 1);
        acc += __shfl_xor(acc, 2);
        if (kc == 0 && jm < NJOB)
            ws[((size_t)b * 16 + qc) * NJOB + jm] = acc;
    }

    __threadfence();          // ws visible device-wide (cross-XCD)
    cg::this_grid().sync();   // all partials written

    // ---------- phase 2a: reduce the 16 partial tables for this b ----------
    if (tid < NJOB) {
        const float* pp = ws + (size_t)b * 16 * NJOB + tid;
        float t = 0.0f;
#pragma unroll
        for (int s = 0; s < 16; ++s) t += pp[s * NJOB];
        Traw[tid / NM][tid % NM] = t;
    }
    __syncthreads();

    // ---------- phase 2b: factorial-scaled tables over j+i<=8 ----------
    if (tid < NH * 45) {
        const int hh = tid / 45;
        int mm = tid % 45, s = 0;
        while (mm > s) { mm -= s + 1; ++s; }
        const int j = mm, i = s - mm;          // j+i = s <= 8
        float fj = 1.0f, fi = 1.0f;
        for (int t = 2; t <= j; ++t) fj *= (float)t;
        for (int t = 2; t <= i; ++t) fi *= (float)t;
        const float invf = 1.0f / (fj * fi);
        const int id0 = s * (s + 1) / 2 + j;
        const int ida = (s + 1) * (s + 2) / 2 + (j + 1);
        const int idb = (s + 1) * (s + 2) / 2 + j;
        Ts[hh][j][i] = Traw[hh][id0] * invf;
        Ta[hh][j][i] = Traw[hh][ida] * invf;
        Tb[hh][j][i] = Traw[hh][idb] * invf;
    }
    __syncthreads();

    // ---------- phase 2c: q-side dots. thread = (q, head, js) ----------
    {
        const int q   = tid >> 4;
        const int hh2 = (tid >> 2) & 3;
        const int js  = tid & 3;
        const float CF = 0.70710678118654752f;  // 1/sqrt(2) folded into q
        const float qfu = Qf[q][2 * hh2] * CF;
        const float qfv = Qf[q][2 * hh2 + 1] * CF;

        float d = 0.0f, a0 = 0.0f, a1 = 0.0f;
        const float qfu2 = qfu * qfu;
        const float qfu4 = qfu2 * qfu2;
        float A = 1.0f;
        if (js & 1) A *= qfu;
        if (js & 2) A *= qfu2;
#pragma unroll
        for (int t = 0; t < 3; ++t) {
            const int j = js + 4 * t;
            if (j <= 8) {
                float f = A;
#pragma unroll
                for (int i = 0; i <= 8; ++i) {
                    if (i <= 8 - j) {
                        d  = __builtin_fmaf(f, Ts[hh2][j][i], d);
                        a0 = __builtin_fmaf(f, Ta[hh2][j][i], a0);
                        a1 = __builtin_fmaf(f, Tb[hh2][j][i], a1);
                        f *= qfv;
                    }
                }
            }
            A *= qfu4;
        }
        d  += __shfl_xor(d, 1);  d  += __shfl_xor(d, 2);
        a0 += __shfl_xor(a0, 1); a0 += __shfl_xor(a0, 2);
        a1 += __shfl_xor(a1, 1); a1 += __shfl_xor(a1, 2);
        if (js == 0) {
            const float inv = 1.0f / d;
            O[q][2 * hh2]     = a0 * inv;
            O[q][2 * hh2 + 1] = a1 * inv;
        }
    }
    __syncthreads();

    // ---------- phase 2d: projection out = O @ W^T ----------
    if (tid < QB * NW) {
        const int qq = tid >> 3, e = tid & 7;
        float sum = 0.0f;
#pragma unroll
        for (int f = 0; f < NW; ++f) sum = __builtin_fmaf(O[qq][f], W[e * NW + f], sum);
        out[((size_t)(b * SS + qc * QB + qq)) * NW + e] = sum;
    }
}

extern "C" void kernel_launch(void* const* d_in, const int* in_sizes, int n_in,
                              void* d_out, int out_size, void* d_ws, size_t ws_size,
                              hipStream_t stream) {
    const float* x     = (const float*)d_in[0];
    const int*   mask  = (const int*)d_in[1];
    const float* theta = (const float*)d_in[2];
    const float* wout  = (const float*)d_in[3];
    float* out = (float*)d_out;
    float* ws  = (float*)d_ws;

    void* args[] = {(void*)&x, (void*)&mask, (void*)&theta, (void*)&wout,
                    (void*)&ws, (void*)&out};
    hipLaunchCooperativeKernel((const void*)mhaq_fused,
                               dim3(BB * (SS / QB)),  // 256 blocks, 1/CU
                               dim3(1024), args, 0, stream);
}

// Round 8
// 15.192 us; speedup vs baseline: 6.7917x; 6.7917x over previous
//
#include <hip/hip_runtime.h>

// Problem constants (fixed by setup_inputs)
#define BB 16
#define SS 1024
#define NW 8
#define QB 64
#define NH 4

// Raw moments T[j][i] = sum_k (mf*u)^j (mf*v)^i over keys, j+i <= 9 (55, triangle
// index m = s(s+1)/2 + j with s=j+i). Weights use Taylor(exp, deg 8): j+i<=8.
__global__ __launch_bounds__(256)
void mhaq_one(const float* __restrict__ x, const int* __restrict__ mask,
              const float* __restrict__ theta, const float* __restrict__ wout,
              float* __restrict__ out)
{
    __shared__ float2 P[NH][SS];     // (u*mf, v*mf) per head/key: 32 KB
    __shared__ float  Qf[QB][NW];    // unmasked q features (this chunk)
    __shared__ float  O[QB][NW];     // attention outputs pre-projection
    __shared__ float  W[64];
    __shared__ float  Traw[NH][55];
    __shared__ float  Ts[NH][9][12], Ta[NH][9][12], Tb[NH][9][12];
    __shared__ int    CMcnt;         // masked-key count

    const int tid = threadIdx.x;
    const int b   = blockIdx.x >> 4;
    const int qc  = blockIdx.x & 15;

    if (tid == 0) CMcnt = 0;

    float th[NW];
#pragma unroll
    for (int e = 0; e < NW; ++e) th[e] = theta[e];

    // ---------- P1: features for all 1024 rows of batch b (4 rows/thread) ----------
    int localMasked = 0;
#pragma unroll
    for (int c = 0; c < 4; ++c) {
        const int row = tid + 256 * c;
        const float* xr = x + ((size_t)b * SS + row) * NW;
        const float4 r0 = *reinterpret_cast<const float4*>(xr);
        const float4 r1 = *reinterpret_cast<const float4*>(xr + 4);
        float g[NW];
        g[0] = __cosf(r0.x + th[0]); g[1] = __cosf(r0.y + th[1]);
        g[2] = __cosf(r0.z + th[2]); g[3] = __cosf(r0.w + th[3]);
        g[4] = __cosf(r1.x + th[4]); g[5] = __cosf(r1.y + th[5]);
        g[6] = __cosf(r1.z + th[6]); g[7] = __cosf(r1.w + th[7]);
        float h[NW];
        h[1] = g[0] * g[1]; h[2] = h[1] * g[2]; h[3] = h[2] * g[3];
        h[4] = h[3] * g[4]; h[5] = h[4] * g[5]; h[6] = h[5] * g[6];
        h[7] = h[6] * g[7];
        h[0] = (g[1] * g[2]) * (g[3] * g[4]) * ((g[5] * g[6]) * g[7]);
        const float mf = (mask[b * SS + row] != 0) ? 1.0f : 0.0f;
        localMasked += (mf == 0.0f) ? 1 : 0;
#pragma unroll
        for (int hd = 0; hd < NH; ++hd)
            P[hd][row] = make_float2(h[2 * hd] * mf, h[2 * hd + 1] * mf);
        const int r = row - qc * QB;
        if ((unsigned)r < (unsigned)QB) {
            *reinterpret_cast<float4*>(&Qf[r][0]) = make_float4(h[0], h[1], h[2], h[3]);
            *reinterpret_cast<float4*>(&Qf[r][4]) = make_float4(h[4], h[5], h[6], h[7]);
        }
    }
    if (localMasked) atomicAdd(&CMcnt, localMasked);
    if (tid < 64) W[tid] = wout[tid];
    __syncthreads();

    // ---------- P2: full moment table; wave = head, lane = key slice ----------
    {
        const int hd = tid >> 6, lane = tid & 63;
        float acc[55];
#pragma unroll
        for (int m = 1; m < 55; ++m) acc[m] = 0.0f;
#pragma unroll 4
        for (int c = 0; c < 16; ++c) {
            const float2 uv = P[hd][c * 64 + lane];
            float muj[10], mvi[10];
            muj[0] = 1.0f; muj[1] = uv.x;
            mvi[0] = 1.0f; mvi[1] = uv.y;
#pragma unroll
            for (int j = 2; j <= 9; ++j) { muj[j] = muj[j - 1] * uv.x; mvi[j] = mvi[j - 1] * uv.y; }
#pragma unroll
            for (int s = 1; s <= 9; ++s)
#pragma unroll
                for (int j = 0; j <= s; ++j)
                    acc[s * (s + 1) / 2 + j] =
                        __builtin_fmaf(muj[j], mvi[s - j], acc[s * (s + 1) / 2 + j]);
        }
#pragma unroll
        for (int st = 1; st <= 32; st <<= 1)
#pragma unroll
            for (int m = 1; m < 55; ++m) acc[m] += __shfl_xor(acc[m], st);
        if (lane == 0) {
            Traw[hd][0] = (float)(SS - CMcnt);  // moment (0,0) = unmasked count
#pragma unroll
            for (int m = 1; m < 55; ++m) Traw[hd][m] = acc[m];
        }
    }
    __syncthreads();

    // ---------- P3: factorial-scaled tables (j+i <= 8) ----------
    if (tid < NH * 45) {
        const int hh = tid / 45;
        int mm = tid % 45, s = 0;
        while (mm > s) { mm -= s + 1; ++s; }
        const int j = mm, i = s - mm;
        float fj = 1.0f, fi = 1.0f;
        for (int t = 2; t <= j; ++t) fj *= (float)t;
        for (int t = 2; t <= i; ++t) fi *= (float)t;
        const float invf = 1.0f / (fj * fi);
        const int id0 = s * (s + 1) / 2 + j;
        const int ida = (s + 1) * (s + 2) / 2 + (j + 1);
        const int idb = (s + 1) * (s + 2) / 2 + j;
        Ts[hh][j][i] = Traw[hh][id0] * invf;
        Ta[hh][j][i] = Traw[hh][ida] * invf;
        Tb[hh][j][i] = Traw[hh][idb] * invf;
    }
    __syncthreads();

    // ---------- P4: q-side dots; thread = (q, head) ----------
    {
        const int q  = tid >> 2;
        const int hh = tid & 3;
        const float CF = 0.70710678118654752f;  // 1/sqrt(head_dim)
        const float qfu = Qf[q][2 * hh] * CF;
        const float qfv = Qf[q][2 * hh + 1] * CF;
        float pu[9], pv[9];
        pu[0] = 1.0f; pv[0] = 1.0f;
#pragma unroll
        for (int j = 1; j <= 8; ++j) { pu[j] = pu[j - 1] * qfu; pv[j] = pv[j - 1] * qfv; }
        float d = 0.0f, a0 = 0.0f, a1 = 0.0f;
#pragma unroll
        for (int s = 0; s <= 8; ++s)
#pragma unroll
            for (int j = 0; j <= s; ++j) {
                const float base = pu[j] * pv[s - j];
                d  = __builtin_fmaf(base, Ts[hh][j][s - j], d);
                a0 = __builtin_fmaf(base, Ta[hh][j][s - j], a0);
                a1 = __builtin_fmaf(base, Tb[hh][j][s - j], a1);
            }
        const float inv = 1.0f / d;
        O[q][2 * hh]     = a0 * inv;
        O[q][2 * hh + 1] = a1 * inv;
    }
    __syncthreads();

    // ---------- P5: projection out = O @ W^T (2 adjacent e per thread) ----------
    {
        const int q  = tid >> 2;
        const int ep = tid & 3;
        float s0 = 0.0f, s1 = 0.0f;
#pragma unroll
        for (int f = 0; f < NW; ++f) {
            s0 = __builtin_fmaf(O[q][f], W[(2 * ep) * NW + f], s0);
            s1 = __builtin_fmaf(O[q][f], W[(2 * ep + 1) * NW + f], s1);
        }
        float* op = out + ((size_t)(b * SS + qc * QB + q)) * NW + 2 * ep;
        *reinterpret_cast<float2*>(op) = make_float2(s0, s1);
    }
}

extern "C" void kernel_launch(void* const* d_in, const int* in_sizes, int n_in,
                              void* d_out, int out_size, void* d_ws, size_t ws_size,
                              hipStream_t stream) {
    const float* x     = (const float*)d_in[0];
    const int*   mask  = (const int*)d_in[1];
    const float* theta = (const float*)d_in[2];
    const float* wout  = (const float*)d_in[3];
    float* out = (float*)d_out;

    mhaq_one<<<dim3(BB * (SS / QB)), dim3(256), 0, stream>>>(x, mask, theta, wout, out);
}